// Round 6
// baseline (345.257 us; speedup 1.0000x reference)
//
#include <hip/hip_runtime.h>

#define DEV __device__ __forceinline__
#define SB0 __builtin_amdgcn_sched_barrier(0)

typedef unsigned short u16;
typedef __attribute__((ext_vector_type(4))) float f32x4;
typedef __attribute__((ext_vector_type(8))) short short8;

DEV u16 f2bf(float f) {
  union { float f; unsigned u; } c; c.f = f;
  unsigned u = c.u;
  unsigned r = (u + 0x7FFFu + ((u >> 16) & 1u)) >> 16;
  return (u16)r;
}
DEV float bf2f(u16 h) {
  union { unsigned u; float f; } c; c.u = ((unsigned)h) << 16;
  return c.f;
}
DEV unsigned cvtpk(float a, float b) {  // D[15:0]=bf16(a), D[31:16]=bf16(b), RNE
  unsigned r;
  asm("v_cvt_pk_bf16_f32 %0, %1, %2" : "=v"(r) : "v"(a), "v"(b));
  return r;
}

DEV void gload16(const void* g, void* l) {
  __builtin_amdgcn_global_load_lds(
      (__attribute__((address_space(1))) void*)(g),
      (__attribute__((address_space(3))) void*)(l), 16, 0, 0);
}
template <int N> DEV void vmcw() {
  if constexpr (N == 0) asm volatile("s_waitcnt vmcnt(0)" ::: "memory");
  else if constexpr (N == 3) asm volatile("s_waitcnt vmcnt(3)" ::: "memory");
  else if constexpr (N == 4) asm volatile("s_waitcnt vmcnt(4)" ::: "memory");
  else if constexpr (N == 8) asm volatile("s_waitcnt vmcnt(8)" ::: "memory");
  SB0;
}

// ---------- merged prep: cast src->bf16 + 5 weight transposes ----------
__global__ __launch_bounds__(256) void prep_kernel(
    const float* __restrict__ src, const float* __restrict__ q_w,
    const float* __restrict__ kv_w, const float* __restrict__ out_w,
    const float* __restrict__ w1, const float* __restrict__ w2,
    u16* __restrict__ Xbf, u16* __restrict__ WqkvT, u16* __restrict__ WoT,
    u16* __restrict__ W1T, u16* __restrict__ W2T) {
  __shared__ float tile[32 * 33];
  int bb = blockIdx.x, tid = threadIdx.x;
  if (bb < 4096) {  // cast 4M floats
    int i = bb * 256 + tid;
    float4 v = reinterpret_cast<const float4*>(src)[i];
    ushort4 o;
    o.x = f2bf(v.x); o.y = f2bf(v.y); o.z = f2bf(v.z); o.w = f2bf(v.w);
    reinterpret_cast<ushort4*>(Xbf)[i] = o;
    return;
  }
  const float* in; u16* outp; int ld_in, ld_out, bx, by;
  if (bb < 5120)       { int t = bb - 4096;  in = q_w;   outp = WqkvT; ld_in = 1024; ld_out = 1024; bx = t & 31;  by = t >> 5; }
  else if (bb < 7168)  { int t = bb - 5120;  in = kv_w;  outp = WqkvT + (size_t)1024 * 1024; ld_in = 2048; ld_out = 1024; bx = t & 63;  by = t >> 6; }
  else if (bb < 8192)  { int t = bb - 7168;  in = out_w; outp = WoT;   ld_in = 1024; ld_out = 1024; bx = t & 31;  by = t >> 5; }
  else if (bb < 12288) { int t = bb - 8192;  in = w1;    outp = W1T;   ld_in = 4096; ld_out = 1024; bx = t & 127; by = t >> 7; }
  else                 { int t = bb - 12288; in = w2;    outp = W2T;   ld_in = 1024; ld_out = 4096; bx = t & 31;  by = t >> 5; }
  int tx = tid & 31, ty = tid >> 5;
  int c0 = bx * 32, r0 = by * 32;
#pragma unroll
  for (int j = 0; j < 4; ++j)
    tile[(ty + j * 8) * 33 + tx] = in[(size_t)(r0 + ty + j * 8) * ld_in + c0 + tx];
  __syncthreads();
#pragma unroll
  for (int j = 0; j < 4; ++j)
    outp[(size_t)(c0 + ty + j * 8) * ld_out + r0 + tx] = f2bf(tile[tx * 33 + ty + j * 8]);
}

// ---------- Vtp extraction (key-permuted V^T; see R4 notes) ----------
__global__ __launch_bounds__(256) void transpose_vtp_kernel(
    const u16* __restrict__ in, u16* __restrict__ out) {
  __shared__ float tile[32][33];
  int c0 = blockIdx.x * 32, r0 = blockIdx.y * 32;  // c0 = dh, r0 = token
  int tx = threadIdx.x, ty = threadIdx.y;
#pragma unroll
  for (int j = 0; j < 4; ++j)
    tile[ty + j * 8][tx] = bf2f(in[(size_t)(r0 + ty + j * 8) * 3072 + 2048 + c0 + tx]);
  __syncthreads();
  int k = r0 + tx;
  int base = k & ~63, kb = k & 63;
  int n = kb >> 4, w = kb & 15;
  int p = ((n >> 1) << 5) | ((w >> 2) << 3) | ((n & 1) << 2) | (w & 3);
#pragma unroll
  for (int j = 0; j < 4; ++j)
    out[(size_t)(c0 + ty + j * 8) * 4096 + base + p] = f2bf(tile[tx][ty + j * 8]);
}

// ---------- generalized ring-3 pipelined GEMM ----------
// C[M,N] = A[M,K_total] * Bt[N,K_total]^T, tile BM x BN, WM x WN waves
// (per-wave (BM/WM) x (BN/WN)). 3 LDS slots, 2 K-tiles prefetched ahead via
// global_load_lds(16B), counted vmcnt (never drains in steady state).
// splitK via blockIdx.z: chunk z at k-offset z*K, writes C + z*c_off; bias
// only from chunk 0. Per-column: col<split -> bias,scale else bias2,1.0.
template <int BM, int BN, int WM, int WN, int OCC, typename OutT, bool RELU>
__global__ __launch_bounds__(WM * WN * 64, OCC) void gemm_ring_kernel(
    const u16* __restrict__ A, int lda,
    const u16* __restrict__ Bt, int ldb,
    const float* __restrict__ bias, const float* __restrict__ bias2, int split,
    OutT* __restrict__ C, int ldc, size_t c_off, int K, float scale) {
  constexpr int NWAVE = WM * WN;
  constexpr int MT = BM / WM / 16;       // m-frags per wave
  constexpr int NF = BN / WN / 16;       // n-frags per wave
  constexpr int LPT = (BM + BN) / 16 / NWAVE;  // gload16 per thread per tile
  constexpr int SLOT = (BM + BN) * 32;   // u16 per slot (A|B)
  __shared__ __align__(16) u16 ring[3][SLOT];

  const int tid = threadIdx.x;
  const int lane = tid & 63, wid = tid >> 6;
  const int wr = wid / WN, wc = wid % WN;
  const int lr = lane & 15, hi = lane >> 4;
  const int z = blockIdx.z;

  // bijective XCD-chunked swizzle (m204)
  const int gx = gridDim.x;
  const int nwg = gx * gridDim.y;
  const int orig = blockIdx.y * gx + blockIdx.x;
  const int q = nwg >> 3, r8 = nwg & 7, xcd = orig & 7, oo = orig >> 3;
  const int lid = (xcd < r8 ? xcd * (q + 1) : r8 * (q + 1) + (xcd - r8) * q) + oo;
  const int rb = lid / gx, cb = lid % gx;

  const u16* Abase = A + (size_t)rb * BM * lda + (size_t)z * K;
  const u16* Bbase = Bt + (size_t)cb * BN * ldb + (size_t)z * K;
  C += (size_t)z * c_off;

  auto stage = [&](int slot, int kt) {
#pragma unroll
    for (int j = 0; j < LPT; ++j) {
      int u = wid * LPT + j;                 // 16-row unit in A|B concat
      int rloc = u * 16 + (lane >> 2);       // concat row
      int cs = (lane & 3) ^ ((rloc >> 1) & 3);
      const u16* src;
      if (u < BM / 16) src = Abase + (size_t)rloc * lda + kt * 32 + cs * 8;
      else src = Bbase + (size_t)(rloc - BM) * ldb + kt * 32 + cs * 8;
      gload16(src, &ring[slot][u * 512]);
    }
  };

  f32x4 acc[MT][NF];
  const f32x4 zero = {0.f, 0.f, 0.f, 0.f};
#pragma unroll
  for (int m = 0; m < MT; ++m)
#pragma unroll
    for (int n = 0; n < NF; ++n) acc[m][n] = zero;

  const int NT = K >> 5;
  stage(0, 0); stage(1, 1);
  vmcw<LPT>();
  __builtin_amdgcn_s_barrier(); SB0;

  const int sw = (lr >> 1) & 3;
  int sl = 0, st = 2;  // read slot, stage slot
  for (int k = 0; k < NT; ++k) {
    const u16* la = &ring[sl][0];
    const u16* lb = &ring[sl][BM * 32];
    short8 bf[NF], af[MT];
#pragma unroll
    for (int n = 0; n < NF; ++n)
      bf[n] = *(const short8*)(lb + (wc * (BN / WN) + n * 16 + lr) * 32 + ((hi ^ sw) * 8));
#pragma unroll
    for (int m = 0; m < MT; ++m)
      af[m] = *(const short8*)(la + (wr * (BM / WM) + m * 16 + lr) * 32 + ((hi ^ sw) * 8));
    if (k + 2 < NT) stage(st, k + 2);
    __builtin_amdgcn_s_setprio(1);
#pragma unroll
    for (int m = 0; m < MT; ++m)
#pragma unroll
      for (int n = 0; n < NF; ++n)
        acc[m][n] = __builtin_amdgcn_mfma_f32_16x16x32_bf16(af[m], bf[n], acc[m][n], 0, 0, 0);
    __builtin_amdgcn_s_setprio(0);
    if (k + 2 < NT) vmcw<LPT>();
    else if (k + 1 < NT) vmcw<0>();
    __builtin_amdgcn_s_barrier(); SB0;
    sl = (sl == 2) ? 0 : sl + 1;
    st = (st == 2) ? 0 : st + 1;
  }

#pragma unroll
  for (int m = 0; m < MT; ++m) {
    int row0 = rb * BM + wr * (BM / WM) + m * 16 + hi * 4;
#pragma unroll
    for (int n = 0; n < NF; ++n) {
      int col = cb * BN + wc * (BN / WN) + n * 16 + lr;
      float sc = (col < split) ? scale : 1.0f;
      float bv = 0.0f;
      if (z == 0) bv = (col < split) ? bias[col] : bias2[col - split];
#pragma unroll
      for (int r = 0; r < 4; ++r) {
        float v = (acc[m][n][r] + bv) * sc;
        if (RELU) v = fmaxf(v, 0.0f);
        if constexpr (sizeof(OutT) == 2)
          C[(size_t)(row0 + r) * ldc + col] = f2bf(v);
        else
          C[(size_t)(row0 + r) * ldc + col] = v;
      }
    }
  }
}

// ---------- fused flash attention (unchanged from R5) ----------
__global__ __launch_bounds__(512, 2) void attn_kernel(
    const u16* __restrict__ QKV, const u16* __restrict__ Vtp,
    const int* __restrict__ mask, u16* __restrict__ CTX) {
  __shared__ __align__(16) u16 kl[2][64 * 64];
  __shared__ __align__(16) u16 vl[2][64 * 64];
  __shared__ unsigned long long mask_lds[16];
  const int lane = threadIdx.x & 63;
  const int wid = threadIdx.x >> 6;
  const int lr = lane & 15, hi = lane >> 4;
  const int bh = blockIdx.x, qt = blockIdx.y;
  const int b = bh >> 4, h = bh & 15;

  const size_t qrow = (size_t)(b * 1024 + qt * 128 + wid * 16 + lr);
  short8 qf[2];
#pragma unroll
  for (int ks = 0; ks < 2; ++ks)
    qf[ks] = *(const short8*)(QKV + qrow * 3072 + h * 64 + ks * 32 + hi * 8);

#pragma unroll
  for (int i = 0; i < 2; ++i) {
    int kt = wid * 2 + i;
    unsigned long long bal = __ballot(mask[b * 1024 + kt * 64 + lane] != 0);
    if (lane == 0) mask_lds[kt] = bal;
  }

  const u16* Kbase = QKV + (size_t)(b * 1024) * 3072 + 1024 + h * 64;
  const u16* Vbase = Vtp + (size_t)(h * 64) * 4096 + b * 1024;

  auto stage = [&](int bf, int kt) {
    int r = wid * 8 + (lane >> 3);
    int cs = (lane & 7) ^ (r & 7);
    gload16(Kbase + (size_t)(kt * 64 + r) * 3072 + cs * 8, &kl[bf][wid * 8 * 64]);
    gload16(Vbase + (size_t)r * 4096 + kt * 64 + cs * 8, &vl[bf][wid * 8 * 64]);
  };

  float m_run = -3.0e38f, l_run = 0.0f;
  f32x4 O[4];
  const f32x4 zero = {0.f, 0.f, 0.f, 0.f};
#pragma unroll
  for (int d = 0; d < 4; ++d) O[d] = zero;

  stage(0, 0);
  __syncthreads();
  int cur = 0;
  for (int kt = 0; kt < 16; ++kt) {
    if (kt + 1 < 16) stage(cur ^ 1, kt + 1);

    f32x4 s[4];
#pragma unroll
    for (int n = 0; n < 4; ++n) s[n] = zero;
    __builtin_amdgcn_s_setprio(1);
#pragma unroll
    for (int n = 0; n < 4; ++n) {
      int key = n * 16 + lr;
#pragma unroll
      for (int ks = 0; ks < 2; ++ks) {
        int ch = (hi + 4 * ks) ^ (key & 7);
        short8 kf = *(const short8*)(kl[cur] + key * 64 + ch * 8);
        s[n] = __builtin_amdgcn_mfma_f32_16x16x32_bf16(kf, qf[ks], s[n], 0, 0, 0);
      }
    }
    __builtin_amdgcn_s_setprio(0);

    unsigned long long mk = mask_lds[kt];
    if (mk != ~0ull) {
#pragma unroll
      for (int n = 0; n < 4; ++n)
#pragma unroll
        for (int r = 0; r < 4; ++r)
          if (!((mk >> (n * 16 + hi * 4 + r)) & 1ull)) s[n][r] = -3.0e38f;
    }

    float tm = -3.0e38f;
#pragma unroll
    for (int n = 0; n < 4; ++n)
      tm = fmaxf(tm, fmaxf(fmaxf(s[n][0], s[n][1]), fmaxf(s[n][2], s[n][3])));
    tm = fmaxf(tm, __shfl_xor(tm, 16));
    tm = fmaxf(tm, __shfl_xor(tm, 32));

    float mo = m_run;
    bool grow = __any(tm > mo);
    float mn = grow ? fmaxf(mo, tm) : mo;
    m_run = mn;
    float ps = 0.0f;
#pragma unroll
    for (int n = 0; n < 4; ++n)
#pragma unroll
      for (int r = 0; r < 4; ++r) {
        float p = __expf(s[n][r] - mn);
        s[n][r] = p;
        ps += p;
      }
    if (grow) {
      float alpha = __expf(mo - mn);
      l_run = l_run * alpha + ps;
#pragma unroll
      for (int d = 0; d < 4; ++d)
#pragma unroll
        for (int r = 0; r < 4; ++r) O[d][r] *= alpha;
    } else {
      l_run += ps;
    }

#pragma unroll
    for (int ks = 0; ks < 2; ++ks) {
      union { unsigned u[4]; short8 s8; } pf;
      pf.u[0] = cvtpk(s[2 * ks][0], s[2 * ks][1]);
      pf.u[1] = cvtpk(s[2 * ks][2], s[2 * ks][3]);
      pf.u[2] = cvtpk(s[2 * ks + 1][0], s[2 * ks + 1][1]);
      pf.u[3] = cvtpk(s[2 * ks + 1][2], s[2 * ks + 1][3]);
      __builtin_amdgcn_s_setprio(1);
#pragma unroll
      for (int d = 0; d < 4; ++d) {
        int vrow = d * 16 + lr;
        int ch = (hi + 4 * ks) ^ (vrow & 7);
        short8 vf = *(const short8*)(vl[cur] + vrow * 64 + ch * 8);
        O[d] = __builtin_amdgcn_mfma_f32_16x16x32_bf16(vf, pf.s8, O[d], 0, 0, 0);
      }
      __builtin_amdgcn_s_setprio(0);
    }
    __syncthreads();
    cur ^= 1;
  }

  float l = l_run;
  l += __shfl_xor(l, 16);
  l += __shfl_xor(l, 32);
  float inv = 1.0f / l;
#pragma unroll
  for (int dt = 0; dt < 4; ++dt) {
    uint2 w;
    w.x = cvtpk(O[dt][0] * inv, O[dt][1] * inv);
    w.y = cvtpk(O[dt][2] * inv, O[dt][3] * inv);
    *(uint2*)(CTX + qrow * 1024 + h * 64 + dt * 16 + hi * 4) = w;
  }
}

// ---------- allennlp LayerNorm of (xa+xb[+xc]) ----------
__global__ __launch_bounds__(256) void ln_kernel(
    const float* __restrict__ xa, const float* __restrict__ xb,
    const float* __restrict__ xc,
    const float* __restrict__ g, const float* __restrict__ beta,
    float* __restrict__ of, u16* __restrict__ ob) {
  int row = blockIdx.x;
  int tid = threadIdx.x;
  const float* pa = xa + (size_t)row * 1024;
  const float* pb = xb + (size_t)row * 1024;
  const float* pc = xc ? xc + (size_t)row * 1024 : nullptr;
  float v[4];
  float s = 0.f, s2 = 0.f;
#pragma unroll
  for (int j = 0; j < 4; ++j) {
    int c = tid + j * 256;
    float x = pa[c] + pb[c];
    if (pc) x += pc[c];
    v[j] = x; s += x; s2 += x * x;
  }
#pragma unroll
  for (int d = 1; d < 64; d <<= 1) {
    s += __shfl_xor(s, d);
    s2 += __shfl_xor(s2, d);
  }
  __shared__ float red[8];
  int w = tid >> 6, lane = tid & 63;
  if (lane == 0) { red[w] = s; red[4 + w] = s2; }
  __syncthreads();
  s = red[0] + red[1] + red[2] + red[3];
  s2 = red[4] + red[5] + red[6] + red[7];
  float mean = s * (1.0f / 1024.0f);
  float var = fmaxf((s2 - 1024.0f * mean * mean) * (1.0f / 1023.0f), 0.0f);
  float rden = 1.0f / (sqrtf(var) + 1e-6f);
#pragma unroll
  for (int j = 0; j < 4; ++j) {
    int c = tid + j * 256;
    float y = g[c] * (v[j] - mean) * rden + beta[c];
    of[(size_t)row * 1024 + c] = y;
    if (ob) ob[(size_t)row * 1024 + c] = f2bf(y);
  }
}

extern "C" void kernel_launch(void* const* d_in, const int* in_sizes, int n_in,
                              void* d_out, int out_size, void* d_ws, size_t ws_size,
                              hipStream_t stream) {
  const float* src   = (const float*)d_in[0];
  const int*   mask  = (const int*)d_in[1];
  const float* q_w   = (const float*)d_in[2];
  const float* q_b   = (const float*)d_in[3];
  const float* kv_w  = (const float*)d_in[4];
  const float* kv_b  = (const float*)d_in[5];
  const float* out_w = (const float*)d_in[6];
  const float* out_b = (const float*)d_in[7];
  const float* w1    = (const float*)d_in[8];
  const float* b1    = (const float*)d_in[9];
  const float* w2    = (const float*)d_in[10];
  const float* b2    = (const float*)d_in[11];
  const float* g1    = (const float*)d_in[12];
  const float* be1   = (const float*)d_in[13];
  const float* g2    = (const float*)d_in[14];
  const float* be2   = (const float*)d_in[15];
  float* out = (float*)d_out;

  char* ws = (char*)d_ws;
  const size_t MB = 1024 * 1024;
  const int BIG = 1 << 30;
  u16*  Xbf   = (u16*)(ws + 0);          //  8MB (4096x1024), dead after QKV
  u16*  CTX   = (u16*)(ws + 8 * MB);     //  8MB
  u16*  WqkvT = (u16*)(ws + 16 * MB);    //  6MB
  u16*  WoT   = (u16*)(ws + 22 * MB);    //  2MB
  u16*  W1T   = (u16*)(ws + 24 * MB);    //  8MB
  u16*  W2T   = (u16*)(ws + 32 * MB);    //  8MB
  u16*  QKV   = (u16*)(ws + 40 * MB);    // 24MB, dead after attn
  u16*  Vtp   = (u16*)(ws + 64 * MB);    //  8MB, dead after attn
  u16*  F1b   = (u16*)(ws + 40 * MB);    // 32MB (40-72), aliases QKV+Vtp
  float* AOUT = (float*)(ws + 72 * MB);  // 16MB, dead after LN1
  float* FP0  = (float*)(ws + 72 * MB);  // 16MB FFN2 partial 0 (aliases AOUT)
  float* FP1  = (float*)(ws + 88 * MB);  // 16MB FFN2 partial 1
  float* OUT1F= (float*)(ws + 104 * MB); // 16MB
  u16*  OUT1B = (u16*)(ws + 0);          //  8MB (aliases Xbf, dead)

  // 1. prep: cast src + all weight transposes
  prep_kernel<<<dim3(16384), dim3(256), 0, stream>>>(
      src, q_w, kv_w, out_w, w1, w2, Xbf, WqkvT, WoT, W1T, W2T);
  // 2. QKV = X @ [q_w|kv_w] + [q_b|kv_b]; Q cols scaled 1/8  (384 blocks, 2/CU)
  gemm_ring_kernel<256, 128, 4, 2, 4, u16, false><<<dim3(24, 16), dim3(512), 0, stream>>>(
      Xbf, 1024, WqkvT, 1024, q_b, kv_b, 1024, QKV, 3072, 0, 1024, 0.125f);
  // 3. Vtp[dh][tok] = V (key-permuted per 64-block)
  transpose_vtp_kernel<<<dim3(32, 128), dim3(32, 8), 0, stream>>>(QKV, Vtp);
  // 4. fused attention -> CTX
  attn_kernel<<<dim3(64, 8), dim3(512), 0, stream>>>(QKV, Vtp, mask, CTX);
  // 5. attn_out = CTX @ out_w + out_b  (128x64 tiles: 512 blocks, 2/CU)
  gemm_ring_kernel<128, 64, 2, 2, 3, float, false><<<dim3(16, 32), dim3(256), 0, stream>>>(
      CTX, 1024, WoT, 1024, out_b, nullptr, BIG, AOUT, 1024, 0, 1024, 1.0f);
  // 6. out1 = LN(src + attn_out)
  ln_kernel<<<dim3(4096), dim3(256), 0, stream>>>(src, AOUT, nullptr, g1, be1, OUT1F, OUT1B);
  // 7. ffn1 = relu(out1 @ w1 + b1)  (512 blocks, 2/CU)
  gemm_ring_kernel<256, 128, 4, 2, 4, u16, true><<<dim3(32, 16), dim3(512), 0, stream>>>(
      OUT1B, 1024, W1T, 1024, b1, nullptr, BIG, F1b, 4096, 0, 1024, 1.0f);
  // 8. ffn2 partials: splitK=2 (512 blocks, 2/CU), chunk0 adds bias
  gemm_ring_kernel<128, 128, 2, 2, 3, float, false><<<dim3(8, 32, 2), dim3(256), 0, stream>>>(
      F1b, 4096, W2T, 4096, b2, nullptr, BIG, FP0, 1024,
      (size_t)(FP1 - FP0), 2048, 1.0f);
  // 9. out = LN(out1 + FP0 + FP1)
  ln_kernel<<<dim3(4096), dim3(256), 0, stream>>>(OUT1F, FP0, FP1, g2, be2, out, nullptr);
  (void)in_sizes; (void)n_in; (void)out_size; (void)ws_size;
}

// Round 9
// 325.582 us; speedup vs baseline: 1.0604x; 1.0604x over previous
//
#include <hip/hip_runtime.h>

#define DEV __device__ __forceinline__
#define SB0 __builtin_amdgcn_sched_barrier(0)

typedef unsigned short u16;
typedef __attribute__((ext_vector_type(4))) float f32x4;
typedef __attribute__((ext_vector_type(8))) short short8;

DEV u16 f2bf(float f) {
  union { float f; unsigned u; } c; c.f = f;
  unsigned u = c.u;
  unsigned r = (u + 0x7FFFu + ((u >> 16) & 1u)) >> 16;
  return (u16)r;
}
DEV float bf2f(u16 h) {
  union { unsigned u; float f; } c; c.u = ((unsigned)h) << 16;
  return c.f;
}
DEV unsigned cvtpk(float a, float b) {  // D[15:0]=bf16(a), D[31:16]=bf16(b), RNE
  unsigned r;
  asm("v_cvt_pk_bf16_f32 %0, %1, %2" : "=v"(r) : "v"(a), "v"(b));
  return r;
}

DEV void gload16(const void* g, void* l) {
  __builtin_amdgcn_global_load_lds(
      (__attribute__((address_space(1))) void*)(g),
      (__attribute__((address_space(3))) void*)(l), 16, 0, 0);
}
template <int N> DEV void vmcw() {
  if constexpr (N == 0) asm volatile("s_waitcnt vmcnt(0)" ::: "memory");
  else if constexpr (N == 8) asm volatile("s_waitcnt vmcnt(8)" ::: "memory");
  SB0;
}

// ---------- merged prep: cast src->bf16 + 5 weight transposes ----------
__global__ __launch_bounds__(256) void prep_kernel(
    const float* __restrict__ src, const float* __restrict__ q_w,
    const float* __restrict__ kv_w, const float* __restrict__ out_w,
    const float* __restrict__ w1, const float* __restrict__ w2,
    u16* __restrict__ Xbf, u16* __restrict__ WqkvT, u16* __restrict__ WoT,
    u16* __restrict__ W1T, u16* __restrict__ W2T) {
  __shared__ float tile[32 * 33];
  int bb = blockIdx.x, tid = threadIdx.x;
  if (bb < 4096) {  // cast 4M floats
    int i = bb * 256 + tid;
    float4 v = reinterpret_cast<const float4*>(src)[i];
    ushort4 o;
    o.x = f2bf(v.x); o.y = f2bf(v.y); o.z = f2bf(v.z); o.w = f2bf(v.w);
    reinterpret_cast<ushort4*>(Xbf)[i] = o;
    return;
  }
  const float* in; u16* outp; int ld_in, ld_out, bx, by;
  if (bb < 5120)       { int t = bb - 4096;  in = q_w;   outp = WqkvT; ld_in = 1024; ld_out = 1024; bx = t & 31;  by = t >> 5; }
  else if (bb < 7168)  { int t = bb - 5120;  in = kv_w;  outp = WqkvT + (size_t)1024 * 1024; ld_in = 2048; ld_out = 1024; bx = t & 63;  by = t >> 6; }
  else if (bb < 8192)  { int t = bb - 7168;  in = out_w; outp = WoT;   ld_in = 1024; ld_out = 1024; bx = t & 31;  by = t >> 5; }
  else if (bb < 12288) { int t = bb - 8192;  in = w1;    outp = W1T;   ld_in = 4096; ld_out = 1024; bx = t & 127; by = t >> 7; }
  else                 { int t = bb - 12288; in = w2;    outp = W2T;   ld_in = 1024; ld_out = 4096; bx = t & 31;  by = t >> 5; }
  int tx = tid & 31, ty = tid >> 5;
  int c0 = bx * 32, r0 = by * 32;
#pragma unroll
  for (int j = 0; j < 4; ++j)
    tile[(ty + j * 8) * 33 + tx] = in[(size_t)(r0 + ty + j * 8) * ld_in + c0 + tx];
  __syncthreads();
#pragma unroll
  for (int j = 0; j < 4; ++j)
    outp[(size_t)(c0 + ty + j * 8) * ld_out + r0 + tx] = f2bf(tile[tx * 33 + ty + j * 8]);
}

// ---------- Vtp extraction (key-permuted V^T; see R4 notes) ----------
__global__ __launch_bounds__(256) void transpose_vtp_kernel(
    const u16* __restrict__ in, u16* __restrict__ out) {
  __shared__ float tile[32][33];
  int c0 = blockIdx.x * 32, r0 = blockIdx.y * 32;  // c0 = dh, r0 = token
  int tx = threadIdx.x, ty = threadIdx.y;
#pragma unroll
  for (int j = 0; j < 4; ++j)
    tile[ty + j * 8][tx] = bf2f(in[(size_t)(r0 + ty + j * 8) * 3072 + 2048 + c0 + tx]);
  __syncthreads();
  int k = r0 + tx;
  int base = k & ~63, kb = k & 63;
  int n = kb >> 4, w = kb & 15;
  int p = ((n >> 1) << 5) | ((w >> 2) << 3) | ((n & 1) << 2) | (w & 3);
#pragma unroll
  for (int j = 0; j < 4; ++j)
    out[(size_t)(c0 + ty + j * 8) * 4096 + base + p] = f2bf(tile[tx][ty + j * 8]);
}

// ---------- generalized ring pipelined GEMM ----------
// C[M,N] = A[M,K_total]*Bt[N,K_total]^T, tile BM x BN, WM x WN waves.
// RING LDS slots, RING-1 K-tiles prefetched ahead via global_load_lds(16B),
// counted vmcnt per K-tile (never drains in steady state). splitK via
// blockIdx.z (k-offset z*K, C += z*c_off, bias from chunk 0 only).
template <int BM, int BN, int WM, int WN, int RING, int OCC, typename OutT, bool RELU>
__global__ __launch_bounds__(WM * WN * 64, OCC) void gemm_ring_kernel(
    const u16* __restrict__ A, int lda,
    const u16* __restrict__ Bt, int ldb,
    const float* __restrict__ bias, const float* __restrict__ bias2, int split,
    OutT* __restrict__ C, int ldc, size_t c_off, int K, float scale) {
  constexpr int NWAVE = WM * WN;
  constexpr int MT = BM / WM / 16;
  constexpr int NF = BN / WN / 16;
  constexpr int LPT = (BM + BN) / 16 / NWAVE;   // gload16/thread/tile (=4 here)
  constexpr int DEPTH = RING - 1;
  constexpr int SLOT = (BM + BN) * 32;
  static_assert(LPT == 4, "vmcnt constants assume LPT==4");
  __shared__ __align__(16) u16 ring[RING][SLOT];

  const int tid = threadIdx.x;
  const int lane = tid & 63, wid = tid >> 6;
  const int wr = wid / WN, wc = wid % WN;
  const int lr = lane & 15, hi = lane >> 4;
  const int z = blockIdx.z;

  // bijective XCD-chunked swizzle (m204)
  const int gx = gridDim.x;
  const int nwg = gx * gridDim.y;
  const int orig = blockIdx.y * gx + blockIdx.x;
  const int q = nwg >> 3, r8 = nwg & 7, xcd = orig & 7, oo = orig >> 3;
  const int lid = (xcd < r8 ? xcd * (q + 1) : r8 * (q + 1) + (xcd - r8) * q) + oo;
  const int rb = lid / gx, cb = lid % gx;

  const u16* Abase = A + (size_t)rb * BM * lda + (size_t)z * K;
  const u16* Bbase = Bt + (size_t)cb * BN * ldb + (size_t)z * K;
  C += (size_t)z * c_off;

  auto stage = [&](int slot, int kt) {
#pragma unroll
    for (int j = 0; j < LPT; ++j) {
      int u = wid * LPT + j;                 // 16-row unit in A|B concat
      int rloc = u * 16 + (lane >> 2);
      int cs = (lane & 3) ^ ((rloc >> 1) & 3);
      const u16* src;
      if (u < BM / 16) src = Abase + (size_t)rloc * lda + kt * 32 + cs * 8;
      else src = Bbase + (size_t)(rloc - BM) * ldb + kt * 32 + cs * 8;
      gload16(src, &ring[slot][u * 512]);
    }
  };

  f32x4 acc[MT][NF];
  const f32x4 zero = {0.f, 0.f, 0.f, 0.f};
#pragma unroll
  for (int m = 0; m < MT; ++m)
#pragma unroll
    for (int n = 0; n < NF; ++n) acc[m][n] = zero;

  const int NT = K >> 5;
  stage(0, 0); stage(1, 1); stage(2, 2);
  vmcw<8>();
  __builtin_amdgcn_s_barrier(); SB0;

  const int sw = (lr >> 1) & 3;
  int sl = 0, st = DEPTH;
  for (int k = 0; k < NT; ++k) {
    const u16* la = &ring[sl][0];
    const u16* lb = &ring[sl][BM * 32];
    short8 bf[NF], af[MT];
#pragma unroll
    for (int n = 0; n < NF; ++n)
      bf[n] = *(const short8*)(lb + (wc * (BN / WN) + n * 16 + lr) * 32 + ((hi ^ sw) * 8));
#pragma unroll
    for (int m = 0; m < MT; ++m)
      af[m] = *(const short8*)(la + (wr * (BM / WM) + m * 16 + lr) * 32 + ((hi ^ sw) * 8));
    if (k + DEPTH < NT) stage(st, k + DEPTH);
    __builtin_amdgcn_s_setprio(1);
#pragma unroll
    for (int m = 0; m < MT; ++m)
#pragma unroll
      for (int n = 0; n < NF; ++n)
        acc[m][n] = __builtin_amdgcn_mfma_f32_16x16x32_bf16(af[m], bf[n], acc[m][n], 0, 0, 0);
    __builtin_amdgcn_s_setprio(0);
    if (k + RING < NT) vmcw<8>();
    else if (k + 1 < NT) vmcw<0>();
    __builtin_amdgcn_s_barrier(); SB0;
    sl = (sl == RING - 1) ? 0 : sl + 1;
    st = (st == RING - 1) ? 0 : st + 1;
  }

#pragma unroll
  for (int m = 0; m < MT; ++m) {
    int row0 = rb * BM + wr * (BM / WM) + m * 16 + hi * 4;
#pragma unroll
    for (int n = 0; n < NF; ++n) {
      int col = cb * BN + wc * (BN / WN) + n * 16 + lr;
      float sc = (col < split) ? scale : 1.0f;
      float bv = 0.0f;
      if (z == 0) bv = (col < split) ? bias[col] : bias2[col - split];
#pragma unroll
      for (int r = 0; r < 4; ++r) {
        float v = (acc[m][n][r] + bv) * sc;
        if (RELU) v = fmaxf(v, 0.0f);
        if constexpr (sizeof(OutT) == 2)
          C[(size_t)(row0 + r) * ldc + col] = f2bf(v);
        else
          C[(size_t)(row0 + r) * ldc + col] = v;
      }
    }
  }
}

// ---------- fused flash attention (unchanged from R5) ----------
__global__ __launch_bounds__(512, 2) void attn_kernel(
    const u16* __restrict__ QKV, const u16* __restrict__ Vtp,
    const int* __restrict__ mask, u16* __restrict__ CTX) {
  __shared__ __align__(16) u16 kl[2][64 * 64];
  __shared__ __align__(16) u16 vl[2][64 * 64];
  __shared__ unsigned long long mask_lds[16];
  const int lane = threadIdx.x & 63;
  const int wid = threadIdx.x >> 6;
  const int lr = lane & 15, hi = lane >> 4;
  const int bh = blockIdx.x, qt = blockIdx.y;
  const int b = bh >> 4, h = bh & 15;

  const size_t qrow = (size_t)(b * 1024 + qt * 128 + wid * 16 + lr);
  short8 qf[2];
#pragma unroll
  for (int ks = 0; ks < 2; ++ks)
    qf[ks] = *(const short8*)(QKV + qrow * 3072 + h * 64 + ks * 32 + hi * 8);

#pragma unroll
  for (int i = 0; i < 2; ++i) {
    int kt = wid * 2 + i;
    unsigned long long bal = __ballot(mask[b * 1024 + kt * 64 + lane] != 0);
    if (lane == 0) mask_lds[kt] = bal;
  }

  const u16* Kbase = QKV + (size_t)(b * 1024) * 3072 + 1024 + h * 64;
  const u16* Vbase = Vtp + (size_t)(h * 64) * 4096 + b * 1024;

  auto stage = [&](int bf, int kt) {
    int r = wid * 8 + (lane >> 3);
    int cs = (lane & 7) ^ (r & 7);
    gload16(Kbase + (size_t)(kt * 64 + r) * 3072 + cs * 8, &kl[bf][wid * 8 * 64]);
    gload16(Vbase + (size_t)r * 4096 + kt * 64 + cs * 8, &vl[bf][wid * 8 * 64]);
  };

  float m_run = -3.0e38f, l_run = 0.0f;
  f32x4 O[4];
  const f32x4 zero = {0.f, 0.f, 0.f, 0.f};
#pragma unroll
  for (int d = 0; d < 4; ++d) O[d] = zero;

  stage(0, 0);
  __syncthreads();
  int cur = 0;
  for (int kt = 0; kt < 16; ++kt) {
    if (kt + 1 < 16) stage(cur ^ 1, kt + 1);

    f32x4 s[4];
#pragma unroll
    for (int n = 0; n < 4; ++n) s[n] = zero;
    __builtin_amdgcn_s_setprio(1);
#pragma unroll
    for (int n = 0; n < 4; ++n) {
      int key = n * 16 + lr;
#pragma unroll
      for (int ks = 0; ks < 2; ++ks) {
        int ch = (hi + 4 * ks) ^ (key & 7);
        short8 kf = *(const short8*)(kl[cur] + key * 64 + ch * 8);
        s[n] = __builtin_amdgcn_mfma_f32_16x16x32_bf16(kf, qf[ks], s[n], 0, 0, 0);
      }
    }
    __builtin_amdgcn_s_setprio(0);

    unsigned long long mk = mask_lds[kt];
    if (mk != ~0ull) {
#pragma unroll
      for (int n = 0; n < 4; ++n)
#pragma unroll
        for (int r = 0; r < 4; ++r)
          if (!((mk >> (n * 16 + hi * 4 + r)) & 1ull)) s[n][r] = -3.0e38f;
    }

    float tm = -3.0e38f;
#pragma unroll
    for (int n = 0; n < 4; ++n)
      tm = fmaxf(tm, fmaxf(fmaxf(s[n][0], s[n][1]), fmaxf(s[n][2], s[n][3])));
    tm = fmaxf(tm, __shfl_xor(tm, 16));
    tm = fmaxf(tm, __shfl_xor(tm, 32));

    float mo = m_run;
    bool grow = __any(tm > mo);
    float mn = grow ? fmaxf(mo, tm) : mo;
    m_run = mn;
    float ps = 0.0f;
#pragma unroll
    for (int n = 0; n < 4; ++n)
#pragma unroll
      for (int r = 0; r < 4; ++r) {
        float p = __expf(s[n][r] - mn);
        s[n][r] = p;
        ps += p;
      }
    if (grow) {
      float alpha = __expf(mo - mn);
      l_run = l_run * alpha + ps;
#pragma unroll
      for (int d = 0; d < 4; ++d)
#pragma unroll
        for (int r = 0; r < 4; ++r) O[d][r] *= alpha;
    } else {
      l_run += ps;
    }

#pragma unroll
    for (int ks = 0; ks < 2; ++ks) {
      union { unsigned u[4]; short8 s8; } pf;
      pf.u[0] = cvtpk(s[2 * ks][0], s[2 * ks][1]);
      pf.u[1] = cvtpk(s[2 * ks][2], s[2 * ks][3]);
      pf.u[2] = cvtpk(s[2 * ks + 1][0], s[2 * ks + 1][1]);
      pf.u[3] = cvtpk(s[2 * ks + 1][2], s[2 * ks + 1][3]);
      __builtin_amdgcn_s_setprio(1);
#pragma unroll
      for (int d = 0; d < 4; ++d) {
        int vrow = d * 16 + lr;
        int ch = (hi + 4 * ks) ^ (vrow & 7);
        short8 vf = *(const short8*)(vl[cur] + vrow * 64 + ch * 8);
        O[d] = __builtin_amdgcn_mfma_f32_16x16x32_bf16(vf, pf.s8, O[d], 0, 0, 0);
      }
      __builtin_amdgcn_s_setprio(0);
    }
    __syncthreads();
    cur ^= 1;
  }

  float l = l_run;
  l += __shfl_xor(l, 16);
  l += __shfl_xor(l, 32);
  float inv = 1.0f / l;
#pragma unroll
  for (int dt = 0; dt < 4; ++dt) {
    uint2 w;
    w.x = cvtpk(O[dt][0] * inv, O[dt][1] * inv);
    w.y = cvtpk(O[dt][2] * inv, O[dt][3] * inv);
    *(uint2*)(CTX + qrow * 1024 + h * 64 + dt * 16 + hi * 4) = w;
  }
}

// ---------- allennlp LayerNorm of (xa+xb[+xc]) ----------
__global__ __launch_bounds__(256) void ln_kernel(
    const float* __restrict__ xa, const float* __restrict__ xb,
    const float* __restrict__ xc,
    const float* __restrict__ g, const float* __restrict__ beta,
    float* __restrict__ of, u16* __restrict__ ob) {
  int row = blockIdx.x;
  int tid = threadIdx.x;
  const float* pa = xa + (size_t)row * 1024;
  const float* pb = xb + (size_t)row * 1024;
  const float* pc = xc ? xc + (size_t)row * 1024 : nullptr;
  float v[4];
  float s = 0.f, s2 = 0.f;
#pragma unroll
  for (int j = 0; j < 4; ++j) {
    int c = tid + j * 256;
    float x = pa[c] + pb[c];
    if (pc) x += pc[c];
    v[j] = x; s += x; s2 += x * x;
  }
#pragma unroll
  for (int d = 1; d < 64; d <<= 1) {
    s += __shfl_xor(s, d);
    s2 += __shfl_xor(s2, d);
  }
  __shared__ float red[8];
  int w = tid >> 6, lane = tid & 63;
  if (lane == 0) { red[w] = s; red[4 + w] = s2; }
  __syncthreads();
  s = red[0] + red[1] + red[2] + red[3];
  s2 = red[4] + red[5] + red[6] + red[7];
  float mean = s * (1.0f / 1024.0f);
  float var = fmaxf((s2 - 1024.0f * mean * mean) * (1.0f / 1023.0f), 0.0f);
  float rden = 1.0f / (sqrtf(var) + 1e-6f);
#pragma unroll
  for (int j = 0; j < 4; ++j) {
    int c = tid + j * 256;
    float y = g[c] * (v[j] - mean) * rden + beta[c];
    of[(size_t)row * 1024 + c] = y;
    if (ob) ob[(size_t)row * 1024 + c] = f2bf(y);
  }
}

extern "C" void kernel_launch(void* const* d_in, const int* in_sizes, int n_in,
                              void* d_out, int out_size, void* d_ws, size_t ws_size,
                              hipStream_t stream) {
  const float* src   = (const float*)d_in[0];
  const int*   mask  = (const int*)d_in[1];
  const float* q_w   = (const float*)d_in[2];
  const float* q_b   = (const float*)d_in[3];
  const float* kv_w  = (const float*)d_in[4];
  const float* kv_b  = (const float*)d_in[5];
  const float* out_w = (const float*)d_in[6];
  const float* out_b = (const float*)d_in[7];
  const float* w1    = (const float*)d_in[8];
  const float* b1    = (const float*)d_in[9];
  const float* w2    = (const float*)d_in[10];
  const float* b2    = (const float*)d_in[11];
  const float* g1    = (const float*)d_in[12];
  const float* be1   = (const float*)d_in[13];
  const float* g2    = (const float*)d_in[14];
  const float* be2   = (const float*)d_in[15];
  float* out = (float*)d_out;

  char* ws = (char*)d_ws;
  const size_t MB = 1024 * 1024;
  const int BIG = 1 << 30;
  u16*  Xbf   = (u16*)(ws + 0);          //  8MB, dead after QKV
  u16*  CTX   = (u16*)(ws + 8 * MB);     //  8MB
  u16*  WqkvT = (u16*)(ws + 16 * MB);    //  6MB
  u16*  WoT   = (u16*)(ws + 22 * MB);    //  2MB
  u16*  W1T   = (u16*)(ws + 24 * MB);    //  8MB
  u16*  W2T   = (u16*)(ws + 32 * MB);    //  8MB
  u16*  QKV   = (u16*)(ws + 40 * MB);    // 24MB, dead after attn
  u16*  Vtp   = (u16*)(ws + 64 * MB);    //  8MB, dead after attn
  u16*  F1b   = (u16*)(ws + 40 * MB);    // 32MB, aliases QKV+Vtp
  float* AOUT = (float*)(ws + 72 * MB);  // 16MB, dead after LN1
  float* FP0  = (float*)(ws + 72 * MB);  // 16MB FFN2 partial 0 (aliases AOUT)
  float* FP1  = (float*)(ws + 88 * MB);  // 16MB FFN2 partial 1
  float* OUT1F= (float*)(ws + 104 * MB); // 16MB
  u16*  OUT1B = (u16*)(ws + 0);          //  8MB (aliases Xbf, dead)

  // 1. prep: cast src + all weight transposes
  prep_kernel<<<dim3(16384), dim3(256), 0, stream>>>(
      src, q_w, kv_w, out_w, w1, w2, Xbf, WqkvT, WoT, W1T, W2T);
  // 2. QKV = X @ [q_w|kv_w] + [q_b|kv_b]; Q cols scaled 1/8  (256x256, 8 waves, ring-4)
  gemm_ring_kernel<256, 256, 2, 4, 4, 2, u16, false><<<dim3(12, 16), dim3(512), 0, stream>>>(
      Xbf, 1024, WqkvT, 1024, q_b, kv_b, 1024, QKV, 3072, 0, 1024, 0.125f);
  // 3. Vtp[dh][tok] = V (key-permuted per 64-block)
  transpose_vtp_kernel<<<dim3(32, 128), dim3(32, 8), 0, stream>>>(QKV, Vtp);
  // 4. fused attention -> CTX
  attn_kernel<<<dim3(64, 8), dim3(512), 0, stream>>>(QKV, Vtp, mask, CTX);
  // 5. attn_out = CTX @ out_w + out_b  (128x128, 4 waves, ring-4)
  gemm_ring_kernel<128, 128, 2, 2, 4, 2, float, false><<<dim3(8, 32), dim3(256), 0, stream>>>(
      CTX, 1024, WoT, 1024, out_b, nullptr, BIG, AOUT, 1024, 0, 1024, 1.0f);
  // 6. out1 = LN(src + attn_out)
  ln_kernel<<<dim3(4096), dim3(256), 0, stream>>>(src, AOUT, nullptr, g1, be1, OUT1F, OUT1B);
  // 7. ffn1 = relu(out1 @ w1 + b1)  (256x256, 8 waves, ring-4)
  gemm_ring_kernel<256, 256, 2, 4, 4, 2, u16, true><<<dim3(16, 16), dim3(512), 0, stream>>>(
      OUT1B, 1024, W1T, 1024, b1, nullptr, BIG, F1b, 4096, 0, 1024, 1.0f);
  // 8. ffn2 partials: splitK=2 + ring-4: 512 blocks, 2/CU, depth-3
  gemm_ring_kernel<128, 128, 2, 2, 4, 2, float, false><<<dim3(8, 32, 2), dim3(256), 0, stream>>>(
      F1b, 4096, W2T, 4096, b2, nullptr, BIG, FP0, 1024,
      (size_t)(FP1 - FP0), 2048, 1.0f);
  // 9. out = LN(out1 + FP0 + FP1)
  ln_kernel<<<dim3(4096), dim3(256), 0, stream>>>(OUT1F, FP0, FP1, g2, be2, out, nullptr);
  (void)in_sizes; (void)n_in; (void)out_size; (void)ws_size;
}